// Round 14
// baseline (2725.491 us; speedup 1.0000x reference)
//
#include <hip/hip_runtime.h>
#include <cstdint>
#include <cstddef>

#define D_   4096
#define H_   32
#define HD_  128
#define F_   11008
#define L_   2
#define R_   64
#define BB   2
#define SS   1024
#define TOK  (BB*SS)
#define N3   12288          // fused QKV output width
#define EPS_ 1e-5f

typedef __attribute__((ext_vector_type(8))) short          s16x8;
typedef __attribute__((ext_vector_type(4))) float          fx4;
typedef __attribute__((ext_vector_type(4))) unsigned short u16x4t;
typedef __attribute__((ext_vector_type(8))) unsigned short u16x8t;

__device__ __forceinline__ unsigned short f2bf(float f) {
  union { float f; unsigned u; } x; x.f = f;
  unsigned r = (x.u + 0x7FFFu + ((x.u >> 16) & 1u)) >> 16;
  return (unsigned short)r;
}
__device__ __forceinline__ float b2f(unsigned short h) {
  union { unsigned u; float f; } x; x.u = ((unsigned)h) << 16;
  return x.f;
}

// Bijective XCD-chunk swizzle (m204), M-fastest decode.
__device__ __forceinline__ void xcd_remap(int nwg, int mt_cnt, int& mt, int& nt) {
  const int orig = blockIdx.x;
  const int q = nwg >> 3, r = nwg & 7;
  const int xcd = orig & 7, i = orig >> 3;
  const int wgid = (xcd < r ? xcd * (q + 1) : r * (q + 1) + (xcd - r) * q) + i;
  mt = wgid % mt_cnt;
  nt = wgid / mt_cnt;
}

// ---------------------------------------------------------------------------
// Embedding gather
// ---------------------------------------------------------------------------
__global__ void k_embed(const int* __restrict__ ids, const float* __restrict__ emb,
                        float* __restrict__ x) {
  const int tok = blockIdx.x, tid = threadIdx.x;
  const int id = ids[tok];
  const float* s = emb + (size_t)id * D_;
  float* d = x + (size_t)tok * D_;
#pragma unroll
  for (int i = 0; i < 4; ++i)
    *(fx4*)(d + i * 1024 + tid * 4) = *(const fx4*)(s + i * 1024 + tid * 4);
}

// ---------------------------------------------------------------------------
// f32 -> bf16 streaming convert; up to 3 sources (blockIdx.y selects slab)
// ---------------------------------------------------------------------------
__global__ __launch_bounds__(256) void k_cvtN(const float* __restrict__ s0,
                                              const float* __restrict__ s1,
                                              const float* __restrict__ s2,
                                              unsigned short* __restrict__ dst, int n) {
  const float* src = blockIdx.y == 0 ? s0 : (blockIdx.y == 1 ? s1 : s2);
  unsigned short* d = dst + (size_t)blockIdx.y * n;
  const int stride = gridDim.x * 256 * 8;
  for (int i = (blockIdx.x * 256 + threadIdx.x) * 8; i < n; i += stride) {
    fx4 a = *(const fx4*)(src + i);
    fx4 b = *(const fx4*)(src + i + 4);
    u16x8t p;
    p[0] = f2bf(a[0]); p[1] = f2bf(a[1]); p[2] = f2bf(a[2]); p[3] = f2bf(a[3]);
    p[4] = f2bf(b[0]); p[5] = f2bf(b[1]); p[6] = f2bf(b[2]); p[7] = f2bf(b[3]);
    *(u16x8t*)(d + i) = p;
  }
}

// ---------------------------------------------------------------------------
// RMSNorm row -> bf16
// ---------------------------------------------------------------------------
__global__ __launch_bounds__(256) void k_rmsnorm(const float* __restrict__ x,
                                                 const float* __restrict__ w,
                                                 unsigned short* __restrict__ out) {
  const int row = blockIdx.x, tid = threadIdx.x;
  const float* xr = x + (size_t)row * D_;
  fx4 v[4];
  float ss = 0.f;
#pragma unroll
  for (int i = 0; i < 4; ++i) {
    v[i] = *(const fx4*)(xr + i * 1024 + tid * 4);
    ss += v[i][0]*v[i][0] + v[i][1]*v[i][1] + v[i][2]*v[i][2] + v[i][3]*v[i][3];
  }
#pragma unroll
  for (int off = 32; off > 0; off >>= 1) ss += __shfl_down(ss, off);
  __shared__ float red[4];
  if ((tid & 63) == 0) red[tid >> 6] = ss;
  __syncthreads();
  const float sc = rsqrtf((red[0] + red[1] + red[2] + red[3]) * (1.f / D_) + EPS_);
  unsigned short* orow = out + (size_t)row * D_;
#pragma unroll
  for (int i = 0; i < 4; ++i) {
    fx4 wv = *(const fx4*)(w + i * 1024 + tid * 4);
    u16x4t pk;
    pk.x = f2bf(v[i][0] * sc * wv[0]);
    pk.y = f2bf(v[i][1] * sc * wv[1]);
    pk.z = f2bf(v[i][2] * sc * wv[2]);
    pk.w = f2bf(v[i][3] * sc * wv[3]);
    *(u16x4t*)(orow + i * 1024 + tid * 4) = pk;
  }
}

// ---------------------------------------------------------------------------
// LoRA mid: part[ks][m][c] = sum_{k in ks-slice} A_bf16[m,k] * Astack[c,k]
// ---------------------------------------------------------------------------
template <int NFRAG>
__global__ __launch_bounds__(256, 2) void k_lmid(const unsigned short* __restrict__ Ain,
                                                 const float* __restrict__ P0,
                                                 const float* __restrict__ P1,
                                                 const float* __restrict__ P2,
                                                 float* __restrict__ part) {
  __shared__ unsigned short sA[64 * 64];
  __shared__ unsigned short sW[NFRAG * 16 * 72];
  const int tid = threadIdx.x, wave = tid >> 6, lane = tid & 63;
  const int l15 = lane & 15, l4 = lane >> 4;
  const int m0 = blockIdx.x * 64;
  const int kbase = blockIdx.y * 512;
  const int arow = tid >> 3;
  const int acol = (((tid & 7) ^ (arow & 7)) << 3);
  const int brow = tid >> 4;
  const int bcol = (tid & 15) << 2;
  const float* ptrs[3] = {P0, P1, P2};

  fx4 acc[NFRAG];
#pragma unroll
  for (int j = 0; j < NFRAG; ++j) acc[j] = (fx4){0.f, 0.f, 0.f, 0.f};

  for (int t = 0; t < 8; ++t) {
    const int kb = kbase + t * 64;
#pragma unroll
    for (int i = 0; i < 2; ++i) {
      const unsigned short* gp = Ain + (size_t)(m0 + i * 32 + arow) * 4096 + kb + acol;
      unsigned short* lp = sA + i * 2048 + wave * 512;
      __builtin_amdgcn_global_load_lds(
          (const __attribute__((address_space(1))) unsigned int*)gp,
          (__attribute__((address_space(3))) unsigned int*)lp, 16, 0, 0);
    }
#pragma unroll
    for (int j = 0; j < NFRAG; ++j) {
      const float* wp = ptrs[j >> 2] + (size_t)((j & 3) * 16 + brow) * 4096 + kb + bcol;
      fx4 v = *(const fx4*)wp;
      u16x4t pk;
      pk.x = f2bf(v[0]); pk.y = f2bf(v[1]); pk.z = f2bf(v[2]); pk.w = f2bf(v[3]);
      *(u16x4t*)&sW[(j * 16 + brow) * 72 + bcol] = pk;
    }
    __syncthreads();
#pragma unroll
    for (int ks = 0; ks < 2; ++ks) {
      const int row = wave * 16 + l15;
      const int cid = (((ks * 4) + l4) ^ (row & 7)) << 3;
      s16x8 af = *(const s16x8*)&sA[row * 64 + cid];
#pragma unroll
      for (int j = 0; j < NFRAG; ++j) {
        s16x8 bf = *(const s16x8*)&sW[(j * 16 + l15) * 72 + ks * 32 + (l4 << 3)];
        acc[j] = __builtin_amdgcn_mfma_f32_16x16x32_bf16(af, bf, acc[j], 0, 0, 0);
      }
    }
    __syncthreads();
  }
  const size_t base = (size_t)blockIdx.y * 2048 * (NFRAG * 16);
#pragma unroll
  for (int j = 0; j < NFRAG; ++j)
#pragma unroll
    for (int r = 0; r < 4; ++r)
      part[base + (size_t)(m0 + wave * 16 + l4 * 4 + r) * (NFRAG * 16) + j * 16 + l15] = acc[j][r];
}

// Reduce 8 K-split partials, scale by ALPHA/R = 0.25, -> bf16
__global__ void k_lmred(const float* __restrict__ part, unsigned short* __restrict__ outb, int ld) {
  const int idx = blockIdx.x * 256 + threadIdx.x;
  const int stride = 2048 * ld;
  float s = 0.f;
#pragma unroll
  for (int ks = 0; ks < 8; ++ks) s += part[(size_t)ks * stride + idx];
  outb[idx] = f2bf(0.25f * s);
}

// ---------------------------------------------------------------------------
// Main GEMM (single N-tile): C[M,N] = A_bf16[M,K] @ W_bf16[N,K]^T (+ LoRA ext).
// 4 blocks/CU (84 VGPR healthy).
// EPI 2: outF = C + auxF (residual)      EPI 5: outB = bf16(C)
// ---------------------------------------------------------------------------
template <int EPI, bool EXT>
__global__ __launch_bounds__(256, 4) void k_gemm(const unsigned short* __restrict__ A,
                                                 const unsigned short* __restrict__ Wb,
                                                 float* __restrict__ outF,
                                                 unsigned short* __restrict__ outB,
                                                 const float* __restrict__ auxF,
                                                 const unsigned short* __restrict__ Aext,
                                                 int ldaE,
                                                 const unsigned short* __restrict__ Wext,
                                                 int M, int N, int K, int nwg) {
  __shared__ unsigned short sA[128 * 64];
  __shared__ unsigned short sB[128 * 64];
  const int tid = threadIdx.x;
  const int wave = tid >> 6, lane = tid & 63;
  int mt, nt;
  xcd_remap(nwg, M >> 7, mt, nt);
  const int m0 = mt * 128, n0 = nt * 128;
  const int wr = wave >> 1, wc = wave & 1;
  const int l15 = lane & 15, l4 = lane >> 4;

  fx4 acc[4][4];
#pragma unroll
  for (int i = 0; i < 4; ++i)
#pragma unroll
    for (int j = 0; j < 4; ++j) acc[i][j] = (fx4){0.f, 0.f, 0.f, 0.f};

  const int nsteps = K >> 6;
  const int arow = tid >> 3;
  const int acol = (((tid & 7) ^ (arow & 7)) << 3);

  for (int t = 0; t < nsteps; ++t) {
    const int kb = t << 6;
#pragma unroll
    for (int i = 0; i < 4; ++i) {
      const unsigned short* gp = A + (size_t)(m0 + i * 32 + arow) * K + kb + acol;
      unsigned short* lp = sA + i * 2048 + wave * 512;
      __builtin_amdgcn_global_load_lds(
          (const __attribute__((address_space(1))) unsigned int*)gp,
          (__attribute__((address_space(3))) unsigned int*)lp, 16, 0, 0);
    }
#pragma unroll
    for (int i = 0; i < 4; ++i) {
      const unsigned short* gp = Wb + (size_t)(n0 + i * 32 + arow) * K + kb + acol;
      unsigned short* lp = sB + i * 2048 + wave * 512;
      __builtin_amdgcn_global_load_lds(
          (const __attribute__((address_space(1))) unsigned int*)gp,
          (__attribute__((address_space(3))) unsigned int*)lp, 16, 0, 0);
    }
    __syncthreads();
#pragma unroll
    for (int ks = 0; ks < 2; ++ks) {
      s16x8 af[4], bfr[4];
#pragma unroll
      for (int i = 0; i < 4; ++i) {
        int row = wr * 64 + i * 16 + l15;
        int cid = (((ks * 4) + l4) ^ (row & 7)) << 3;
        af[i] = *(const s16x8*)&sA[row * 64 + cid];
      }
#pragma unroll
      for (int j = 0; j < 4; ++j) {
        int row = wc * 64 + j * 16 + l15;
        int cid = (((ks * 4) + l4) ^ (row & 7)) << 3;
        bfr[j] = *(const s16x8*)&sB[row * 64 + cid];
      }
#pragma unroll
      for (int i = 0; i < 4; ++i)
#pragma unroll
        for (int j = 0; j < 4; ++j)
          acc[i][j] = __builtin_amdgcn_mfma_f32_16x16x32_bf16(af[i], bfr[j], acc[i][j], 0, 0, 0);
    }
    __syncthreads();
  }

  if constexpr (EXT) {
    const int third = n0 >> 12;
    const unsigned short* Ae = Aext + third * 64;
    const unsigned short* We = Wext + (size_t)n0 * 64;
#pragma unroll
    for (int i = 0; i < 4; ++i) {
      const unsigned short* gp = Ae + (size_t)(m0 + i * 32 + arow) * ldaE + acol;
      unsigned short* lp = sA + i * 2048 + wave * 512;
      __builtin_amdgcn_global_load_lds(
          (const __attribute__((address_space(1))) unsigned int*)gp,
          (__attribute__((address_space(3))) unsigned int*)lp, 16, 0, 0);
    }
#pragma unroll
    for (int i = 0; i < 4; ++i) {
      const unsigned short* gp = We + (size_t)(i * 32 + arow) * 64 + acol;
      unsigned short* lp = sB + i * 2048 + wave * 512;
      __builtin_amdgcn_global_load_lds(
          (const __attribute__((address_space(1))) unsigned int*)gp,
          (__attribute__((address_space(3))) unsigned int*)lp, 16, 0, 0);
    }
    __syncthreads();
#pragma unroll
    for (int ks = 0; ks < 2; ++ks) {
      s16x8 af[4], bfr[4];
#pragma unroll
      for (int i = 0; i < 4; ++i) {
        int row = wr * 64 + i * 16 + l15;
        int cid = (((ks * 4) + l4) ^ (row & 7)) << 3;
        af[i] = *(const s16x8*)&sA[row * 64 + cid];
      }
#pragma unroll
      for (int j = 0; j < 4; ++j) {
        int row = wc * 64 + j * 16 + l15;
        int cid = (((ks * 4) + l4) ^ (row & 7)) << 3;
        bfr[j] = *(const s16x8*)&sB[row * 64 + cid];
      }
#pragma unroll
      for (int i = 0; i < 4; ++i)
#pragma unroll
        for (int j = 0; j < 4; ++j)
          acc[i][j] = __builtin_amdgcn_mfma_f32_16x16x32_bf16(af[i], bfr[j], acc[i][j], 0, 0, 0);
    }
  }

  const int r0 = m0 + wr * 64 + (l4 << 2);
  const int c0 = n0 + wc * 64 + l15;
#pragma unroll
  for (int i = 0; i < 4; ++i)
#pragma unroll
    for (int j = 0; j < 4; ++j)
#pragma unroll
      for (int r = 0; r < 4; ++r) {
        size_t idx = (size_t)(r0 + i * 16 + r) * N + (c0 + j * 16);
        float v = acc[i][j][r];
        if (EPI == 2) outF[idx] = v + auxF[idx];
        else          outB[idx] = f2bf(v);     // EPI 5
      }
}

// ---------------------------------------------------------------------------
// Dual-N-tile GEMM (gu2-proven structure: 3 LDS streams, 64 MFMA/barrier,
// 2 blocks/CU). Block computes 128x256 of C. Used for QKV (768 blocks).
// EPI 5: outB = bf16(C). EXT: LoRA K-extension for both tiles (same third —
// n0 is 256-aligned, third boundary 4096-aligned).
// ---------------------------------------------------------------------------
template <int EPI, bool EXT>
__global__ __launch_bounds__(256, 2) void k_gemm2(const unsigned short* __restrict__ A,
                                                  const unsigned short* __restrict__ Wb,
                                                  float* __restrict__ outF,
                                                  unsigned short* __restrict__ outB,
                                                  const float* __restrict__ auxF,
                                                  const unsigned short* __restrict__ Aext,
                                                  int ldaE,
                                                  const unsigned short* __restrict__ Wext,
                                                  int M, int N, int K, int nwg) {
  __shared__ unsigned short sA[128 * 64];
  __shared__ unsigned short sB0[128 * 64];
  __shared__ unsigned short sB1[128 * 64];
  const int tid = threadIdx.x;
  const int wave = tid >> 6, lane = tid & 63;
  int mt, nt;
  xcd_remap(nwg, M >> 7, mt, nt);
  const int m0 = mt * 128, n0 = nt * 256;
  const int wr = wave >> 1, wc = wave & 1;
  const int l15 = lane & 15, l4 = lane >> 4;

  fx4 acc0[4][4], acc1[4][4];
#pragma unroll
  for (int i = 0; i < 4; ++i)
#pragma unroll
    for (int j = 0; j < 4; ++j) {
      acc0[i][j] = (fx4){0.f, 0.f, 0.f, 0.f};
      acc1[i][j] = (fx4){0.f, 0.f, 0.f, 0.f};
    }

  const int nsteps = K >> 6;
  const int arow = tid >> 3;
  const int acol = (((tid & 7) ^ (arow & 7)) << 3);

  for (int t = 0; t < nsteps; ++t) {
    const int kb = t << 6;
#pragma unroll
    for (int i = 0; i < 4; ++i) {
      const unsigned short* gp = A + (size_t)(m0 + i * 32 + arow) * K + kb + acol;
      unsigned short* lp = sA + i * 2048 + wave * 512;
      __builtin_amdgcn_global_load_lds(
          (const __attribute__((address_space(1))) unsigned int*)gp,
          (__attribute__((address_space(3))) unsigned int*)lp, 16, 0, 0);
    }
#pragma unroll
    for (int i = 0; i < 4; ++i) {
      const unsigned short* gp = Wb + (size_t)(n0 + i * 32 + arow) * K + kb + acol;
      unsigned short* lp = sB0 + i * 2048 + wave * 512;
      __builtin_amdgcn_global_load_lds(
          (const __attribute__((address_space(1))) unsigned int*)gp,
          (__attribute__((address_space(3))) unsigned int*)lp, 16, 0, 0);
    }
#pragma unroll
    for (int i = 0; i < 4; ++i) {
      const unsigned short* gp = Wb + (size_t)(n0 + 128 + i * 32 + arow) * K + kb + acol;
      unsigned short* lp = sB1 + i * 2048 + wave * 512;
      __builtin_amdgcn_global_load_lds(
          (const __attribute__((address_space(1))) unsigned int*)gp,
          (__attribute__((address_space(3))) unsigned int*)lp, 16, 0, 0);
    }
    __syncthreads();
#pragma unroll
    for (int ks = 0; ks < 2; ++ks) {
      s16x8 af[4], b0[4], b1[4];
#pragma unroll
      for (int i = 0; i < 4; ++i) {
        int row = wr * 64 + i * 16 + l15;
        int cid = (((ks * 4) + l4) ^ (row & 7)) << 3;
        af[i] = *(const s16x8*)&sA[row * 64 + cid];
      }
#pragma unroll
      for (int j = 0; j < 4; ++j) {
        int row = wc * 64 + j * 16 + l15;
        int cid = (((ks * 4) + l4) ^ (row & 7)) << 3;
        b0[j] = *(const s16x8*)&sB0[row * 64 + cid];
        b1[j] = *(const s16x8*)&sB1[row * 64 + cid];
      }
#pragma unroll
      for (int i = 0; i < 4; ++i)
#pragma unroll
        for (int j = 0; j < 4; ++j) {
          acc0[i][j] = __builtin_amdgcn_mfma_f32_16x16x32_bf16(af[i], b0[j], acc0[i][j], 0, 0, 0);
          acc1[i][j] = __builtin_amdgcn_mfma_f32_16x16x32_bf16(af[i], b1[j], acc1[i][j], 0, 0, 0);
        }
    }
    __syncthreads();
  }

  if constexpr (EXT) {
    const int third = n0 >> 12;   // both tiles in same third (256-aligned n0)
    const unsigned short* Ae = Aext + third * 64;
#pragma unroll
    for (int i = 0; i < 4; ++i) {
      const unsigned short* gp = Ae + (size_t)(m0 + i * 32 + arow) * ldaE + acol;
      unsigned short* lp = sA + i * 2048 + wave * 512;
      __builtin_amdgcn_global_load_lds(
          (const __attribute__((address_space(1))) unsigned int*)gp,
          (__attribute__((address_space(3))) unsigned int*)lp, 16, 0, 0);
    }
#pragma unroll
    for (int i = 0; i < 4; ++i) {
      const unsigned short* gp = Wext + (size_t)(n0 + i * 32 + arow) * 64 + acol;
      unsigned short* lp = sB0 + i * 2048 + wave * 512;
      __builtin_amdgcn_global_load_lds(
          (const __attribute__((address_space(1))) unsigned int*)gp,
          (__attribute__((address_space(3))) unsigned int*)lp, 16, 0, 0);
    }
#pragma unroll
    for (int i = 0; i < 4; ++i) {
      const unsigned short* gp = Wext + (size_t)(n0 + 128 + i * 32 + arow) * 64 + acol;
      unsigned short* lp = sB1 + i * 2048 + wave * 512;
      __builtin_amdgcn_global_load_lds(
          (const __attribute__((address_space(1))) unsigned int*)gp,
          (__attribute__((address_space(3))) unsigned int*)lp, 16, 0, 0);
    }
    __syncthreads();
#pragma unroll
    for (int ks = 0; ks < 2; ++ks) {
      s16x8 af[4], b0[4], b1[4];
#pragma unroll
      for (int i = 0; i < 4; ++i) {
        int row = wr * 64 + i * 16 + l15;
        int cid = (((ks * 4) + l4) ^ (row & 7)) << 3;
        af[i] = *(const s16x8*)&sA[row * 64 + cid];
      }
#pragma unroll
      for (int j = 0; j < 4; ++j) {
        int row = wc * 64 + j * 16 + l15;
        int cid = (((ks * 4) + l4) ^ (row & 7)) << 3;
        b0[j] = *(const s16x8*)&sB0[row * 64 + cid];
        b1[j] = *(const s16x8*)&sB1[row * 64 + cid];
      }
#pragma unroll
      for (int i = 0; i < 4; ++i)
#pragma unroll
        for (int j = 0; j < 4; ++j) {
          acc0[i][j] = __builtin_amdgcn_mfma_f32_16x16x32_bf16(af[i], b0[j], acc0[i][j], 0, 0, 0);
          acc1[i][j] = __builtin_amdgcn_mfma_f32_16x16x32_bf16(af[i], b1[j], acc1[i][j], 0, 0, 0);
        }
    }
  }

  const int r0 = m0 + wr * 64 + (l4 << 2);
  const int c0 = n0 + wc * 64 + l15;
#pragma unroll
  for (int i = 0; i < 4; ++i)
#pragma unroll
    for (int j = 0; j < 4; ++j)
#pragma unroll
      for (int r = 0; r < 4; ++r) {
        size_t idx0 = (size_t)(r0 + i * 16 + r) * N + (c0 + j * 16);
        size_t idx1 = idx0 + 128;
        if (EPI == 2) {
          outF[idx0] = acc0[i][j][r] + auxF[idx0];
          outF[idx1] = acc1[i][j][r] + auxF[idx1];
        } else {
          outB[idx0] = f2bf(acc0[i][j][r]);
          outB[idx1] = f2bf(acc1[i][j][r]);
        }
      }
}

// ---------------------------------------------------------------------------
// Fused gate+up GEMM (2 blocks/CU)
// ---------------------------------------------------------------------------
__global__ __launch_bounds__(256, 2) void k_gemm_gu2(const unsigned short* __restrict__ A,
                                                     const unsigned short* __restrict__ Wg,
                                                     const unsigned short* __restrict__ Wu,
                                                     unsigned short* __restrict__ outB,
                                                     int M, int N, int K, int nwg) {
  __shared__ unsigned short sA[128 * 64];
  __shared__ unsigned short sG[128 * 64];
  __shared__ unsigned short sU[128 * 64];
  const int tid = threadIdx.x;
  const int wave = tid >> 6, lane = tid & 63;
  int mt, nt;
  xcd_remap(nwg, M >> 7, mt, nt);
  const int m0 = mt * 128, n0 = nt * 128;
  const int wr = wave >> 1, wc = wave & 1;
  const int l15 = lane & 15, l4 = lane >> 4;

  fx4 accg[4][4], accu[4][4];
#pragma unroll
  for (int i = 0; i < 4; ++i)
#pragma unroll
    for (int j = 0; j < 4; ++j) {
      accg[i][j] = (fx4){0.f, 0.f, 0.f, 0.f};
      accu[i][j] = (fx4){0.f, 0.f, 0.f, 0.f};
    }

  const int nsteps = K >> 6;
  const int arow = tid >> 3;
  const int acol = (((tid & 7) ^ (arow & 7)) << 3);

  for (int t = 0; t < nsteps; ++t) {
    const int kb = t << 6;
#pragma unroll
    for (int i = 0; i < 4; ++i) {
      const unsigned short* gp = A + (size_t)(m0 + i * 32 + arow) * K + kb + acol;
      unsigned short* lp = sA + i * 2048 + wave * 512;
      __builtin_amdgcn_global_load_lds(
          (const __attribute__((address_space(1))) unsigned int*)gp,
          (__attribute__((address_space(3))) unsigned int*)lp, 16, 0, 0);
    }
#pragma unroll
    for (int i = 0; i < 4; ++i) {
      const unsigned short* gp = Wg + (size_t)(n0 + i * 32 + arow) * K + kb + acol;
      unsigned short* lp = sG + i * 2048 + wave * 512;
      __builtin_amdgcn_global_load_lds(
          (const __attribute__((address_space(1))) unsigned int*)gp,
          (__attribute__((address_space(3))) unsigned int*)lp, 16, 0, 0);
    }
#pragma unroll
    for (int i = 0; i < 4; ++i) {
      const unsigned short* gp = Wu + (size_t)(n0 + i * 32 + arow) * K + kb + acol;
      unsigned short* lp = sU + i * 2048 + wave * 512;
      __builtin_amdgcn_global_load_lds(
          (const __attribute__((address_space(1))) unsigned int*)gp,
          (__attribute__((address_space(3))) unsigned int*)lp, 16, 0, 0);
    }
    __syncthreads();
#pragma unroll
    for (int ks = 0; ks < 2; ++ks) {
      s16x8 af[4], bg[4], bu[4];
#pragma unroll
      for (int i = 0; i < 4; ++i) {
        int row = wr * 64 + i * 16 + l15;
        int cid = (((ks * 4) + l4) ^ (row & 7)) << 3;
        af[i] = *(const s16x8*)&sA[row * 64 + cid];
      }
#pragma unroll
      for (int j = 0; j < 4; ++j) {
        int row = wc * 64 + j * 16 + l15;
        int cid = (((ks * 4) + l4) ^ (row & 7)) << 3;
        bg[j] = *(const s16x8*)&sG[row * 64 + cid];
        bu[j] = *(const s16x8*)&sU[row * 64 + cid];
      }
#pragma unroll
      for (int i = 0; i < 4; ++i)
#pragma unroll
        for (int j = 0; j < 4; ++j) {
          accg[i][j] = __builtin_amdgcn_mfma_f32_16x16x32_bf16(af[i], bg[j], accg[i][j], 0, 0, 0);
          accu[i][j] = __builtin_amdgcn_mfma_f32_16x16x32_bf16(af[i], bu[j], accu[i][j], 0, 0, 0);
        }
    }
    __syncthreads();
  }

  const int r0 = m0 + wr * 64 + (l4 << 2);
  const int c0 = n0 + wc * 64 + l15;
#pragma unroll
  for (int i = 0; i < 4; ++i)
#pragma unroll
    for (int j = 0; j < 4; ++j)
#pragma unroll
      for (int r = 0; r < 4; ++r) {
        size_t idx = (size_t)(r0 + i * 16 + r) * N + (c0 + j * 16);
        float g = accg[i][j][r];
        outB[idx] = f2bf(accu[i][j][r] * g / (1.f + __expf(-g)));
      }
}

// ---------------------------------------------------------------------------
// RoPE tables: cos/sin [S][64]
// ---------------------------------------------------------------------------
__global__ void k_ropetab(float* __restrict__ cosT, float* __restrict__ sinT) {
  int idx = blockIdx.x * 256 + threadIdx.x;
  int s = idx >> 6, d = idx & 63;
  float inv = powf(10000.f, -(float)d * (1.f / 64.f));
  float f = (float)s * inv;
  cosT[idx] = cosf(f);
  sinT[idx] = sinf(f);
}

// ---------------------------------------------------------------------------
// K/V prep (once per layer)
// ---------------------------------------------------------------------------
__global__ __launch_bounds__(256) void k_kvprep(const unsigned short* __restrict__ P3,
                                                const float* __restrict__ cosT,
                                                const float* __restrict__ sinT,
                                                unsigned short* __restrict__ kb,
                                                unsigned short* __restrict__ vb) {
  __shared__ unsigned short sT[128 * 72];
  const int tid = threadIdx.x;
  const int bh = blockIdx.y, b = bh >> 5, h = bh & 31;
  const int k0 = blockIdx.x * 64;
  { // K rows: RoPE -> kb (coalesced)
    int row = tid >> 2, part = tid & 3;
    int ksr = k0 + row;
    const unsigned short* kp = P3 + (size_t)(b * SS + ksr) * N3 + 4096 + h * HD_;
    const float* cr = cosT + ksr * 64;
    const float* sr = sinT + ksr * 64;
    unsigned short* kd = kb + ((size_t)bh * SS + ksr) * HD_;
#pragma unroll
    for (int g = 0; g < 2; ++g) {
      int d0 = part * 16 + g * 8;
      u16x8t klo = *(const u16x8t*)(kp + d0);
      u16x8t khi = *(const u16x8t*)(kp + d0 + 64);
      u16x8t wlo, whi;
#pragma unroll
      for (int j = 0; j < 8; ++j) {
        float lo = b2f(klo[j]), hi = b2f(khi[j]);
        float c = cr[d0 + j], s = sr[d0 + j];
        wlo[j] = f2bf(lo * c - hi * s);
        whi[j] = f2bf(hi * c + lo * s);
      }
      *(u16x8t*)(kd + d0)      = wlo;
      *(u16x8t*)(kd + d0 + 64) = whi;
    }
  }
  { // V transpose via LDS -> vb rows
#pragma unroll
    for (int it = 0; it < 8; ++it) {
      int key = it * 8 + (tid >> 5), hd0 = (tid & 31) * 4;
      u16x4t v = *(const u16x4t*)(P3 + (size_t)(b * SS + k0 + key) * N3 + 8192 + h * HD_ + hd0);
      sT[(hd0 + 0) * 72 + key] = v.x;
      sT[(hd0 + 1) * 72 + key] = v.y;
      sT[(hd0 + 2) * 72 + key] = v.z;
      sT[(hd0 + 3) * 72 + key] = v.w;
    }
    __syncthreads();
    int hd = tid >> 1, half = tid & 1;
    unsigned short* vd = vb + ((size_t)bh * HD_ + hd) * SS + k0 + half * 32;
    const unsigned short* ssrc = sT + hd * 72 + half * 32;
#pragma unroll
    for (int j = 0; j < 4; ++j)
      *(u16x8t*)(vd + j * 8) = *(const u16x8t*)(ssrc + j * 8);
  }
}

// ---------------------------------------------------------------------------
// Flash attention (Q-RoPE in-register; K/V DMA from prepped buffers,
// pre-swizzled source + linear LDS + swizzled ds_read)
// ---------------------------------------------------------------------------
__global__ __launch_bounds__(256, 3) void k_attn(const unsigned short* __restrict__ P3,
                                                 const unsigned short* __restrict__ kb,
                                                 const unsigned short* __restrict__ vb,
                                                 const float* __restrict__ cosT,
                                                 const float* __restrict__ sinT,
                                                 const int* __restrict__ am,
                                                 unsigned short* __restrict__ O) {
  __shared__ unsigned short sK[64 * 128];
  __shared__ unsigned short sV[128 * 64];
  __shared__ unsigned short sP[4 * 16 * 72];
  const int tid = threadIdx.x, wave = tid >> 6, lane = tid & 63;
  const int bh = blockIdx.y, b = bh >> 5, h = bh & 31;
  const int qt = (int)gridDim.x - 1 - blockIdx.x;
  const float scale = 0.08838834764831845f;
  const int l15 = lane & 15, l4 = lane >> 4;

  const int qs = qt * 64 + wave * 16 + l15;
  s16x8 qf[4];
  {
    const unsigned short* qp = P3 + (size_t)(b * SS + qs) * N3 + h * HD_;
    const float* cr = cosT + qs * 64;
    const float* sr = sinT + qs * 64;
#pragma unroll
    for (int ks = 0; ks < 2; ++ks) {
      int dlo = ks * 32 + l4 * 8;
      u16x8t qlo = *(const u16x8t*)(qp + dlo);
      u16x8t qhi = *(const u16x8t*)(qp + dlo + 64);
      u16x8t plo, phi;
#pragma unroll
      for (int j = 0; j < 8; ++j) {
        float lo = b2f(qlo[j]), hi = b2f(qhi[j]);
        float c = cr[dlo + j], s = sr[dlo + j];
        plo[j] = f2bf(lo * c - hi * s);
        phi[j] = f2bf(hi * c + lo * s);
      }
      qf[ks]     = *(s16x8*)&plo;
      qf[ks + 2] = *(s16x8*)&phi;
    }
  }

  const int krow_l = lane >> 4, kg = lane & 15;
  const int vrow_l = lane >> 3, vg = lane & 7;

  fx4 oacc[8];
#pragma unroll
  for (int nf = 0; nf < 8; ++nf) oacc[nf] = (fx4){0.f, 0.f, 0.f, 0.f};
  float mrun[4] = {-1e30f, -1e30f, -1e30f, -1e30f};
  float lrun[4] = {0.f, 0.f, 0.f, 0.f};

  const int ntiles = qt + 1;
  for (int kt = 0; kt < ntiles; ++kt) {
    const int k0 = kt * 64;
    __syncthreads();
#pragma unroll
    for (int i = 0; i < 4; ++i) {
      int row = (i * 4 + wave) * 4 + krow_l;
      const unsigned short* gp = kb + ((size_t)bh * SS + k0 + row) * HD_ + ((kg ^ (row & 7)) << 3);
      unsigned short* lp = sK + (i * 4 + wave) * 512;
      __builtin_amdgcn_global_load_lds(
          (const __attribute__((address_space(1))) unsigned int*)gp,
          (__attribute__((address_space(3))) unsigned int*)lp, 16, 0, 0);
    }
#pragma unroll
    for (int i = 0; i < 4; ++i) {
      int row = (i * 4 + wave) * 8 + vrow_l;
      const unsigned short* gp = vb + ((size_t)bh * HD_ + row) * SS + k0 + ((vg ^ (row & 7)) << 3);
      unsigned short* lp = sV + (i * 4 + wave) * 512;
      __builtin_amdgcn_global_load_lds(
          (const __attribute__((address_space(1))) unsigned int*)gp,
          (__attribute__((address_space(3))) unsigned int*)lp, 16, 0, 0);
    }
    __syncthreads();
    if (k0 <= qt * 64 + wave * 16 + 15) {
      fx4 sfr[4];
#pragma unroll
      for (int kf = 0; kf < 4; ++kf) sfr[kf] = (fx4){0.f, 0.f, 0.f, 0.f};
#pragma unroll
      for (int kf = 0; kf < 4; ++kf) {
        int row = kf * 16 + l15;
#pragma unroll
        for (int ks = 0; ks < 4; ++ks) {
          int cid = ((ks * 4 + l4) ^ (row & 7)) << 3;
          s16x8 kfr = *(const s16x8*)&sK[row * 128 + cid];
          sfr[kf] = __builtin_amdgcn_mfma_f32_16x16x32_bf16(qf[ks], kfr, sfr[kf], 0, 0, 0);
        }
      }
      float p[16], corr[4];
#pragma unroll
      for (int r = 0; r < 4; ++r) {
        int qr = qt * 64 + wave * 16 + l4 * 4 + r;
        float mx = -1e30f;
#pragma unroll
        for (int kf = 0; kf < 4; ++kf) {
          int key = k0 + kf * 16 + l15;
          float bb = (key <= qr && am[b * SS + key] != 0) ? 0.f : -1e9f;
          p[kf * 4 + r] = sfr[kf][r] * scale + bb;
          mx = fmaxf(mx, p[kf * 4 + r]);
        }
        mx = fmaxf(mx, __shfl_xor(mx, 1));
        mx = fmaxf(mx, __shfl_xor(mx, 2));
        mx = fmaxf(mx, __shfl_xor(mx, 4));
        mx = fmaxf(mx, __shfl_xor(mx, 8));
        float mn = fmaxf(mrun[r], mx);
        corr[r] = __expf(mrun[r] - mn);
        mrun[r] = mn;
        float rs = 0.f;
#pragma unroll
        for (int kf = 0; kf < 4; ++kf) {
          p[kf * 4 + r] = __expf(p[kf * 4 + r] - mn);
          rs += p[kf * 4 + r];
        }
        rs += __shfl_xor(rs, 1);
        rs += __shfl_xor(rs, 2);
        rs += __shfl_xor(rs, 4);
        rs += __shfl_xor(rs, 8);
        lrun[r] = lrun[r] * corr[r] + rs;
      }
#pragma unroll
      for (int nf = 0; nf < 8; ++nf) {
        oacc[nf][0] *= corr[0];
        oacc[nf][1] *= corr[1];
        oacc[nf][2] *= corr[2];
        oacc[nf][3] *= corr[3];
      }
      unsigned short* pp = sP + wave * (16 * 72);
#pragma unroll
      for (int r = 0; r < 4; ++r) {
        int row = l4 * 4 + r;
#pragma unroll
        for (int kf = 0; kf < 4; ++kf)
          pp[row * 72 + kf * 16 + l15] = f2bf(p[kf * 4 + r]);
      }
      s16x8 pa0 = *(const s16x8*)&pp[l15 * 72 + l4 * 8];
      s16x8 pa1 = *(const s16x8*)&pp[l15 * 72 + 32 + l4 * 8];
#pragma unroll
      for (int nf = 0; nf < 8; ++nf) {
        int row = nf * 16 + l15;
        int c0s = ((0 * 4 + l4) ^ (row & 7)) << 3;
        int c1s = ((1 * 4 + l4) ^ (row & 7)) << 3;
        s16x8 v0 = *(const s16x8*)&sV[row * 64 + c0s];
        s16x8 v1 = *(const s16x8*)&sV[row * 64 + c1s];
        oacc[nf] = __builtin_amdgcn_mfma_f32_16x16x32_bf16(pa0, v0, oacc[nf], 0, 0, 0);
        oacc[nf] = __builtin_amdgcn_mfma_f32_16x16x32_bf16(pa1, v1, oacc[nf], 0, 0, 0);
      }
    }
  }
  const size_t obase = (size_t)b * SS * D_ + h * HD_;
#pragma unroll
  for (int nf = 0; nf < 8; ++nf)
#pragma unroll
    for (int r = 0; r < 4; ++r) {
      int qr = qt * 64 + wave * 16 + l4 * 4 + r;
      O[obase + (size_t)qr * D_ + nf * 16 + l15] = f2bf(oacc[nf][r] / lrun[r]);
    }
}

// ---------------------------------------------------------------------------
// Final RMSNorm + classifier
// ---------------------------------------------------------------------------
__global__ __launch_bounds__(256) void k_final(const float* __restrict__ xf,
                                               const float* __restrict__ fw,
                                               const float* __restrict__ cW,
                                               const float* __restrict__ cb,
                                               float* __restrict__ out) {
  const int b = blockIdx.x, tid = threadIdx.x;
  const float* xr = xf + (size_t)b * SS * D_;
  __shared__ float red[4];
  fx4 v[4];
  float ss = 0.f;
#pragma unroll
  for (int i = 0; i < 4; ++i) {
    v[i] = *(const fx4*)(xr + i * 1024 + tid * 4);
    ss += v[i][0]*v[i][0] + v[i][1]*v[i][1] + v[i][2]*v[i][2] + v[i][3]*v[i][3];
  }
#pragma unroll
  for (int off = 32; off > 0; off >>= 1) ss += __shfl_down(ss, off);
  if ((tid & 63) == 0) red[tid >> 6] = ss;
  __syncthreads();
  const float sc = rsqrtf((red[0] + red[1] + red[2] + red[3]) * (1.f / D_) + EPS_);
  for (int c = 0; c < 3; ++c) {
    float d = 0.f;
#pragma unroll
    for (int i = 0; i < 4; ++i) {
      fx4 fv = *(const fx4*)(fw + i * 1024 + tid * 4);
      fx4 cw = *(const fx4*)(cW + (size_t)c * D_ + i * 1024 + tid * 4);
#pragma unroll
      for (int j = 0; j < 4; ++j) d += v[i][j] * sc * fv[j] * cw[j];
    }
#pragma unroll
    for (int off = 32; off > 0; off >>= 1) d += __shfl_down(d, off);
    __syncthreads();
    if ((tid & 63) == 0) red[tid >> 6] = d;
    __syncthreads();
    if (tid == 0) out[b * 3 + c] = red[0] + red[1] + red[2] + red[3] + cb[c];
  }
}

// ---------------------------------------------------------------------------
extern "C" void kernel_launch(void* const* d_in, const int* in_sizes, int n_in,
                              void* d_out, int out_size, void* d_ws, size_t ws_size,
                              hipStream_t stream) {
  const int*   ids = (const int*)d_in[0];
  const int*   am  = (const int*)d_in[1];
  const float* emb = (const float*)d_in[2];
  const float* Wq  = (const float*)d_in[3];
  const float* Wk  = (const float*)d_in[4];
  const float* Wv  = (const float*)d_in[5];
  const float* Wo  = (const float*)d_in[6];
  const float* Aq  = (const float*)d_in[7];
  const float* Bq  = (const float*)d_in[8];
  const float* Ak  = (const float*)d_in[9];
  const float* Bk  = (const float*)d_in[10];
  const float* Av  = (const float*)d_in[11];
  const float* Bv  = (const float*)d_in[12];
  const float* Ao  = (const float*)d_in[13];
  const float* Bo  = (const float*)d_in[14];
  const float* Wg  = (const float*)d_in[15];
  const float* Wu  = (const float*)d_in[16];
  const float* Wd  = (const float*)d_in[17];
  const float* anw = (const float*)d_in[18];
  const float* mnw = (const float*)d_in[19];
  const float* fnw = (const float*)d_in[20];
  const float* cW  = (const float*)d_in[21];
  const float* cb  = (const float*)d_in[22];
  float* out = (float*)d_out;

  char* w = (char*)d_ws;
  float* xf = (float*)w;                     w += (size_t)TOK * D_ * 4;
  unsigned short* P3 = (unsigned short*)w;   w += (size_t)TOK * N3 * 2;
  unsigned short* gact = (unsigned short*)w; w += (size_t)TOK * F_ * 2;
  unsigned short* hb = (unsigned short*)w;   w += (size_t)TOK * D_ * 2;
  unsigned short* ob = (unsigned short*)w;   w += (size_t)TOK * D_ * 2;
  unsigned short* kbuf = (unsigned short*)w; w += (size_t)TOK * D_ * 2;
  unsigned short* vbuf = (unsigned short*)w; w += (size_t)TOK * D_ * 2;
  unsigned short* Wm3 = (unsigned short*)w;  w += (size_t)3 * D_ * D_ * 2;
  unsigned short* Wgu = (unsigned short*)w;  w += (size_t)2 * F_ * D_ * 2;
  unsigned short* Bx3 = (unsigned short*)w;  w += (size_t)3 * D_ * R_ * 2;
  unsigned short* BxO = (unsigned short*)w;  w += (size_t)D_ * R_ * 2;
  unsigned short* lm3 = (unsigned short*)w;  w += (size_t)TOK * 192 * 2;
  unsigned short* lmo = (unsigned short*)w;  w += (size_t)TOK * 64 * 2;
  float* lm3p = (float*)w;                   w += (size_t)8 * TOK * 192 * 4;
  float* lmop = (float*)w;                   w += (size_t)8 * TOK * 64 * 4;
  float* cosT = (float*)w;                   w += (size_t)SS * 64 * 4;
  float* sinT = (float*)w;                   w += (size_t)SS * 64 * 4;
  if ((size_t)(w - (char*)d_ws) > ws_size) return;

  k_ropetab<<<256, 256, 0, stream>>>(cosT, sinT);
  k_embed<<<TOK, 256, 0, stream>>>(ids, emb, xf);

  const int nwgQKV2 = (TOK / 128) * (N3 / 256);  // 768
  const int nwgProj = (D_ / 128) * (TOK / 128);  // 512
  const int nwgMlp = (F_ / 128) * (TOK / 128);   // 1376
  dim3 gAttn(SS / 64, BB * H_);
  dim3 gPrep(SS / 64, BB * H_);
  dim3 gLmid(TOK / 64, 8);
  const int CVT_BLK = 2048;

  for (int l = 0; l < L_; ++l) {
    const size_t oDD = (size_t)l * D_ * D_;
    const size_t oRD = (size_t)l * R_ * D_;
    const size_t oDR = (size_t)l * D_ * R_;
    const size_t oFD = (size_t)l * F_ * D_;

    k_rmsnorm<<<TOK, 256, 0, stream>>>(xf, anw + (size_t)l * D_, hb);
    // QKV: merged cvt (W x3, B x3), LoRA mid, dual-tile fused GEMM
    k_cvtN<<<dim3(CVT_BLK, 3), 256, 0, stream>>>(Wq + oDD, Wk + oDD, Wv + oDD, Wm3, D_ * D_);
    k_cvtN<<<dim3(128, 3), 256, 0, stream>>>(Bq + oDR, Bk + oDR, Bv + oDR, Bx3, D_ * R_);
    k_lmid<12><<<gLmid, 256, 0, stream>>>(hb, Aq + oRD, Ak + oRD, Av + oRD, lm3p);
    k_lmred<<<TOK * 192 / 256, 256, 0, stream>>>(lm3p, lm3, 192);
    k_gemm2<5, true><<<nwgQKV2, 256, 0, stream>>>(hb, Wm3, nullptr, P3, nullptr,
                                                  lm3, 192, Bx3, TOK, N3, D_, nwgQKV2);
    // K/V prep + attention
    k_kvprep<<<gPrep, 256, 0, stream>>>(P3, cosT, sinT, kbuf, vbuf);
    k_attn<<<gAttn, 256, 0, stream>>>(P3, kbuf, vbuf, cosT, sinT, am, ob);
    // O projection + LoRA ext + residual
    k_cvtN<<<dim3(CVT_BLK, 1), 256, 0, stream>>>(Wo + oDD, nullptr, nullptr, Wm3, D_ * D_);
    k_cvtN<<<dim3(128, 1), 256, 0, stream>>>(Bo + oDR, nullptr, nullptr, BxO, D_ * R_);
    k_lmid<4><<<gLmid, 256, 0, stream>>>(ob, Ao + oRD, Ao + oRD, Ao + oRD, lmop);
    k_lmred<<<TOK * 64 / 256, 256, 0, stream>>>(lmop, lmo, 64);
    k_gemm<2, true><<<nwgProj, 256, 0, stream>>>(ob, Wm3, xf, nullptr, xf,
                                                 lmo, 64, BxO, TOK, D_, D_, nwgProj);
    // MLP
    k_rmsnorm<<<TOK, 256, 0, stream>>>(xf, mnw + (size_t)l * D_, hb);
    k_cvtN<<<dim3(CVT_BLK, 2), 256, 0, stream>>>(Wg + oFD, Wu + oFD, nullptr, Wgu, F_ * D_);
    k_gemm_gu2<<<nwgMlp, 256, 0, stream>>>(hb, Wgu, Wgu + (size_t)F_ * D_, gact, TOK, F_, D_, nwgMlp);
    k_cvtN<<<dim3(CVT_BLK, 1), 256, 0, stream>>>(Wd + oFD, nullptr, nullptr, Wgu, D_ * F_);
    k_gemm<2, false><<<nwgProj, 256, 0, stream>>>(gact, Wgu, xf, nullptr, xf,
                                                  nullptr, 0, nullptr, TOK, D_, F_, nwgProj);
  }

  k_final<<<BB, 256, 0, stream>>>(xf, fnw, cW, cb, out);
  (void)in_sizes; (void)n_in; (void)out_size;
}

// Round 15
// 2663.083 us; speedup vs baseline: 1.0234x; 1.0234x over previous
//
#include <hip/hip_runtime.h>
#include <cstdint>
#include <cstddef>

#define D_   4096
#define H_   32
#define HD_  128
#define F_   11008
#define L_   2
#define R_   64
#define BB   2
#define SS   1024
#define TOK  (BB*SS)
#define N3   12288          // fused QKV output width
#define EPS_ 1e-5f

typedef __attribute__((ext_vector_type(8))) short          s16x8;
typedef __attribute__((ext_vector_type(4))) float          fx4;
typedef __attribute__((ext_vector_type(4))) unsigned short u16x4t;
typedef __attribute__((ext_vector_type(8))) unsigned short u16x8t;

__device__ __forceinline__ unsigned short f2bf(float f) {
  union { float f; unsigned u; } x; x.f = f;
  unsigned r = (x.u + 0x7FFFu + ((x.u >> 16) & 1u)) >> 16;
  return (unsigned short)r;
}
__device__ __forceinline__ float b2f(unsigned short h) {
  union { unsigned u; float f; } x; x.u = ((unsigned)h) << 16;
  return x.f;
}

// Bijective XCD-chunk swizzle (m204), M-fastest decode.
__device__ __forceinline__ void xcd_remap(int nwg, int mt_cnt, int& mt, int& nt) {
  const int orig = blockIdx.x;
  const int q = nwg >> 3, r = nwg & 7;
  const int xcd = orig & 7, i = orig >> 3;
  const int wgid = (xcd < r ? xcd * (q + 1) : r * (q + 1) + (xcd - r) * q) + i;
  mt = wgid % mt_cnt;
  nt = wgid / mt_cnt;
}

// ---------------------------------------------------------------------------
// Embedding gather
// ---------------------------------------------------------------------------
__global__ void k_embed(const int* __restrict__ ids, const float* __restrict__ emb,
                        float* __restrict__ x) {
  const int tok = blockIdx.x, tid = threadIdx.x;
  const int id = ids[tok];
  const float* s = emb + (size_t)id * D_;
  float* d = x + (size_t)tok * D_;
#pragma unroll
  for (int i = 0; i < 4; ++i)
    *(fx4*)(d + i * 1024 + tid * 4) = *(const fx4*)(s + i * 1024 + tid * 4);
}

// ---------------------------------------------------------------------------
// f32 -> bf16 streaming convert; up to 3 sources (blockIdx.y selects slab)
// ---------------------------------------------------------------------------
__global__ __launch_bounds__(256) void k_cvtN(const float* __restrict__ s0,
                                              const float* __restrict__ s1,
                                              const float* __restrict__ s2,
                                              unsigned short* __restrict__ dst, int n) {
  const float* src = blockIdx.y == 0 ? s0 : (blockIdx.y == 1 ? s1 : s2);
  unsigned short* d = dst + (size_t)blockIdx.y * n;
  const int stride = gridDim.x * 256 * 8;
  for (int i = (blockIdx.x * 256 + threadIdx.x) * 8; i < n; i += stride) {
    fx4 a = *(const fx4*)(src + i);
    fx4 b = *(const fx4*)(src + i + 4);
    u16x8t p;
    p[0] = f2bf(a[0]); p[1] = f2bf(a[1]); p[2] = f2bf(a[2]); p[3] = f2bf(a[3]);
    p[4] = f2bf(b[0]); p[5] = f2bf(b[1]); p[6] = f2bf(b[2]); p[7] = f2bf(b[3]);
    *(u16x8t*)(d + i) = p;
  }
}

// ---------------------------------------------------------------------------
// RMSNorm row -> bf16
// ---------------------------------------------------------------------------
__global__ __launch_bounds__(256) void k_rmsnorm(const float* __restrict__ x,
                                                 const float* __restrict__ w,
                                                 unsigned short* __restrict__ out) {
  const int row = blockIdx.x, tid = threadIdx.x;
  const float* xr = x + (size_t)row * D_;
  fx4 v[4];
  float ss = 0.f;
#pragma unroll
  for (int i = 0; i < 4; ++i) {
    v[i] = *(const fx4*)(xr + i * 1024 + tid * 4);
    ss += v[i][0]*v[i][0] + v[i][1]*v[i][1] + v[i][2]*v[i][2] + v[i][3]*v[i][3];
  }
#pragma unroll
  for (int off = 32; off > 0; off >>= 1) ss += __shfl_down(ss, off);
  __shared__ float red[4];
  if ((tid & 63) == 0) red[tid >> 6] = ss;
  __syncthreads();
  const float sc = rsqrtf((red[0] + red[1] + red[2] + red[3]) * (1.f / D_) + EPS_);
  unsigned short* orow = out + (size_t)row * D_;
#pragma unroll
  for (int i = 0; i < 4; ++i) {
    fx4 wv = *(const fx4*)(w + i * 1024 + tid * 4);
    u16x4t pk;
    pk.x = f2bf(v[i][0] * sc * wv[0]);
    pk.y = f2bf(v[i][1] * sc * wv[1]);
    pk.z = f2bf(v[i][2] * sc * wv[2]);
    pk.w = f2bf(v[i][3] * sc * wv[3]);
    *(u16x4t*)(orow + i * 1024 + tid * 4) = pk;
  }
}

// ---------------------------------------------------------------------------
// LoRA mid: part[ks][m][c] = sum_{k in ks-slice} A_bf16[m,k] * Astack[c,k]
// ---------------------------------------------------------------------------
template <int NFRAG>
__global__ __launch_bounds__(256, 2) void k_lmid(const unsigned short* __restrict__ Ain,
                                                 const float* __restrict__ P0,
                                                 const float* __restrict__ P1,
                                                 const float* __restrict__ P2,
                                                 float* __restrict__ part) {
  __shared__ unsigned short sA[64 * 64];
  __shared__ unsigned short sW[NFRAG * 16 * 72];
  const int tid = threadIdx.x, wave = tid >> 6, lane = tid & 63;
  const int l15 = lane & 15, l4 = lane >> 4;
  const int m0 = blockIdx.x * 64;
  const int kbase = blockIdx.y * 512;
  const int arow = tid >> 3;
  const int acol = (((tid & 7) ^ (arow & 7)) << 3);
  const int brow = tid >> 4;
  const int bcol = (tid & 15) << 2;
  const float* ptrs[3] = {P0, P1, P2};

  fx4 acc[NFRAG];
#pragma unroll
  for (int j = 0; j < NFRAG; ++j) acc[j] = (fx4){0.f, 0.f, 0.f, 0.f};

  for (int t = 0; t < 8; ++t) {
    const int kb = kbase + t * 64;
#pragma unroll
    for (int i = 0; i < 2; ++i) {
      const unsigned short* gp = Ain + (size_t)(m0 + i * 32 + arow) * 4096 + kb + acol;
      unsigned short* lp = sA + i * 2048 + wave * 512;
      __builtin_amdgcn_global_load_lds(
          (const __attribute__((address_space(1))) unsigned int*)gp,
          (__attribute__((address_space(3))) unsigned int*)lp, 16, 0, 0);
    }
#pragma unroll
    for (int j = 0; j < NFRAG; ++j) {
      const float* wp = ptrs[j >> 2] + (size_t)((j & 3) * 16 + brow) * 4096 + kb + bcol;
      fx4 v = *(const fx4*)wp;
      u16x4t pk;
      pk.x = f2bf(v[0]); pk.y = f2bf(v[1]); pk.z = f2bf(v[2]); pk.w = f2bf(v[3]);
      *(u16x4t*)&sW[(j * 16 + brow) * 72 + bcol] = pk;
    }
    __syncthreads();
#pragma unroll
    for (int ks = 0; ks < 2; ++ks) {
      const int row = wave * 16 + l15;
      const int cid = (((ks * 4) + l4) ^ (row & 7)) << 3;
      s16x8 af = *(const s16x8*)&sA[row * 64 + cid];
#pragma unroll
      for (int j = 0; j < NFRAG; ++j) {
        s16x8 bf = *(const s16x8*)&sW[(j * 16 + l15) * 72 + ks * 32 + (l4 << 3)];
        acc[j] = __builtin_amdgcn_mfma_f32_16x16x32_bf16(af, bf, acc[j], 0, 0, 0);
      }
    }
    __syncthreads();
  }
  const size_t base = (size_t)blockIdx.y * 2048 * (NFRAG * 16);
#pragma unroll
  for (int j = 0; j < NFRAG; ++j)
#pragma unroll
    for (int r = 0; r < 4; ++r)
      part[base + (size_t)(m0 + wave * 16 + l4 * 4 + r) * (NFRAG * 16) + j * 16 + l15] = acc[j][r];
}

// Reduce 8 K-split partials, scale by ALPHA/R = 0.25, -> bf16
__global__ void k_lmred(const float* __restrict__ part, unsigned short* __restrict__ outb, int ld) {
  const int idx = blockIdx.x * 256 + threadIdx.x;
  const int stride = 2048 * ld;
  float s = 0.f;
#pragma unroll
  for (int ks = 0; ks < 8; ++ks) s += part[(size_t)ks * stride + idx];
  outb[idx] = f2bf(0.25f * s);
}

// ---------------------------------------------------------------------------
// Main GEMM (single N-tile): C[M,N] = A_bf16[M,K] @ W_bf16[N,K]^T (+ LoRA ext).
// 4 blocks/CU (84 VGPR healthy).
// EPI 2: outF = C + auxF (residual)      EPI 5: outB = bf16(C)
// ---------------------------------------------------------------------------
template <int EPI, bool EXT>
__global__ __launch_bounds__(256, 4) void k_gemm(const unsigned short* __restrict__ A,
                                                 const unsigned short* __restrict__ Wb,
                                                 float* __restrict__ outF,
                                                 unsigned short* __restrict__ outB,
                                                 const float* __restrict__ auxF,
                                                 const unsigned short* __restrict__ Aext,
                                                 int ldaE,
                                                 const unsigned short* __restrict__ Wext,
                                                 int M, int N, int K, int nwg) {
  __shared__ unsigned short sA[128 * 64];
  __shared__ unsigned short sB[128 * 64];
  const int tid = threadIdx.x;
  const int wave = tid >> 6, lane = tid & 63;
  int mt, nt;
  xcd_remap(nwg, M >> 7, mt, nt);
  const int m0 = mt * 128, n0 = nt * 128;
  const int wr = wave >> 1, wc = wave & 1;
  const int l15 = lane & 15, l4 = lane >> 4;

  fx4 acc[4][4];
#pragma unroll
  for (int i = 0; i < 4; ++i)
#pragma unroll
    for (int j = 0; j < 4; ++j) acc[i][j] = (fx4){0.f, 0.f, 0.f, 0.f};

  const int nsteps = K >> 6;
  const int arow = tid >> 3;
  const int acol = (((tid & 7) ^ (arow & 7)) << 3);

  for (int t = 0; t < nsteps; ++t) {
    const int kb = t << 6;
#pragma unroll
    for (int i = 0; i < 4; ++i) {
      const unsigned short* gp = A + (size_t)(m0 + i * 32 + arow) * K + kb + acol;
      unsigned short* lp = sA + i * 2048 + wave * 512;
      __builtin_amdgcn_global_load_lds(
          (const __attribute__((address_space(1))) unsigned int*)gp,
          (__attribute__((address_space(3))) unsigned int*)lp, 16, 0, 0);
    }
#pragma unroll
    for (int i = 0; i < 4; ++i) {
      const unsigned short* gp = Wb + (size_t)(n0 + i * 32 + arow) * K + kb + acol;
      unsigned short* lp = sB + i * 2048 + wave * 512;
      __builtin_amdgcn_global_load_lds(
          (const __attribute__((address_space(1))) unsigned int*)gp,
          (__attribute__((address_space(3))) unsigned int*)lp, 16, 0, 0);
    }
    __syncthreads();
#pragma unroll
    for (int ks = 0; ks < 2; ++ks) {
      s16x8 af[4], bfr[4];
#pragma unroll
      for (int i = 0; i < 4; ++i) {
        int row = wr * 64 + i * 16 + l15;
        int cid = (((ks * 4) + l4) ^ (row & 7)) << 3;
        af[i] = *(const s16x8*)&sA[row * 64 + cid];
      }
#pragma unroll
      for (int j = 0; j < 4; ++j) {
        int row = wc * 64 + j * 16 + l15;
        int cid = (((ks * 4) + l4) ^ (row & 7)) << 3;
        bfr[j] = *(const s16x8*)&sB[row * 64 + cid];
      }
#pragma unroll
      for (int i = 0; i < 4; ++i)
#pragma unroll
        for (int j = 0; j < 4; ++j)
          acc[i][j] = __builtin_amdgcn_mfma_f32_16x16x32_bf16(af[i], bfr[j], acc[i][j], 0, 0, 0);
    }
    __syncthreads();
  }

  if constexpr (EXT) {
    const int third = n0 >> 12;
    const unsigned short* Ae = Aext + third * 64;
    const unsigned short* We = Wext + (size_t)n0 * 64;
#pragma unroll
    for (int i = 0; i < 4; ++i) {
      const unsigned short* gp = Ae + (size_t)(m0 + i * 32 + arow) * ldaE + acol;
      unsigned short* lp = sA + i * 2048 + wave * 512;
      __builtin_amdgcn_global_load_lds(
          (const __attribute__((address_space(1))) unsigned int*)gp,
          (__attribute__((address_space(3))) unsigned int*)lp, 16, 0, 0);
    }
#pragma unroll
    for (int i = 0; i < 4; ++i) {
      const unsigned short* gp = We + (size_t)(i * 32 + arow) * 64 + acol;
      unsigned short* lp = sB + i * 2048 + wave * 512;
      __builtin_amdgcn_global_load_lds(
          (const __attribute__((address_space(1))) unsigned int*)gp,
          (__attribute__((address_space(3))) unsigned int*)lp, 16, 0, 0);
    }
    __syncthreads();
#pragma unroll
    for (int ks = 0; ks < 2; ++ks) {
      s16x8 af[4], bfr[4];
#pragma unroll
      for (int i = 0; i < 4; ++i) {
        int row = wr * 64 + i * 16 + l15;
        int cid = (((ks * 4) + l4) ^ (row & 7)) << 3;
        af[i] = *(const s16x8*)&sA[row * 64 + cid];
      }
#pragma unroll
      for (int j = 0; j < 4; ++j) {
        int row = wc * 64 + j * 16 + l15;
        int cid = (((ks * 4) + l4) ^ (row & 7)) << 3;
        bfr[j] = *(const s16x8*)&sB[row * 64 + cid];
      }
#pragma unroll
      for (int i = 0; i < 4; ++i)
#pragma unroll
        for (int j = 0; j < 4; ++j)
          acc[i][j] = __builtin_amdgcn_mfma_f32_16x16x32_bf16(af[i], bfr[j], acc[i][j], 0, 0, 0);
    }
  }

  const int r0 = m0 + wr * 64 + (l4 << 2);
  const int c0 = n0 + wc * 64 + l15;
#pragma unroll
  for (int i = 0; i < 4; ++i)
#pragma unroll
    for (int j = 0; j < 4; ++j)
#pragma unroll
      for (int r = 0; r < 4; ++r) {
        size_t idx = (size_t)(r0 + i * 16 + r) * N + (c0 + j * 16);
        float v = acc[i][j][r];
        if (EPI == 2) outF[idx] = v + auxF[idx];
        else          outB[idx] = f2bf(v);     // EPI 5
      }
}

// ---------------------------------------------------------------------------
// Fused gate+up GEMM (2 blocks/CU)
// ---------------------------------------------------------------------------
__global__ __launch_bounds__(256, 2) void k_gemm_gu2(const unsigned short* __restrict__ A,
                                                     const unsigned short* __restrict__ Wg,
                                                     const unsigned short* __restrict__ Wu,
                                                     unsigned short* __restrict__ outB,
                                                     int M, int N, int K, int nwg) {
  __shared__ unsigned short sA[128 * 64];
  __shared__ unsigned short sG[128 * 64];
  __shared__ unsigned short sU[128 * 64];
  const int tid = threadIdx.x;
  const int wave = tid >> 6, lane = tid & 63;
  int mt, nt;
  xcd_remap(nwg, M >> 7, mt, nt);
  const int m0 = mt * 128, n0 = nt * 128;
  const int wr = wave >> 1, wc = wave & 1;
  const int l15 = lane & 15, l4 = lane >> 4;

  fx4 accg[4][4], accu[4][4];
#pragma unroll
  for (int i = 0; i < 4; ++i)
#pragma unroll
    for (int j = 0; j < 4; ++j) {
      accg[i][j] = (fx4){0.f, 0.f, 0.f, 0.f};
      accu[i][j] = (fx4){0.f, 0.f, 0.f, 0.f};
    }

  const int nsteps = K >> 6;
  const int arow = tid >> 3;
  const int acol = (((tid & 7) ^ (arow & 7)) << 3);

  for (int t = 0; t < nsteps; ++t) {
    const int kb = t << 6;
#pragma unroll
    for (int i = 0; i < 4; ++i) {
      const unsigned short* gp = A + (size_t)(m0 + i * 32 + arow) * K + kb + acol;
      unsigned short* lp = sA + i * 2048 + wave * 512;
      __builtin_amdgcn_global_load_lds(
          (const __attribute__((address_space(1))) unsigned int*)gp,
          (__attribute__((address_space(3))) unsigned int*)lp, 16, 0, 0);
    }
#pragma unroll
    for (int i = 0; i < 4; ++i) {
      const unsigned short* gp = Wg + (size_t)(n0 + i * 32 + arow) * K + kb + acol;
      unsigned short* lp = sG + i * 2048 + wave * 512;
      __builtin_amdgcn_global_load_lds(
          (const __attribute__((address_space(1))) unsigned int*)gp,
          (__attribute__((address_space(3))) unsigned int*)lp, 16, 0, 0);
    }
#pragma unroll
    for (int i = 0; i < 4; ++i) {
      const unsigned short* gp = Wu + (size_t)(n0 + i * 32 + arow) * K + kb + acol;
      unsigned short* lp = sU + i * 2048 + wave * 512;
      __builtin_amdgcn_global_load_lds(
          (const __attribute__((address_space(1))) unsigned int*)gp,
          (__attribute__((address_space(3))) unsigned int*)lp, 16, 0, 0);
    }
    __syncthreads();
#pragma unroll
    for (int ks = 0; ks < 2; ++ks) {
      s16x8 af[4], bg[4], bu[4];
#pragma unroll
      for (int i = 0; i < 4; ++i) {
        int row = wr * 64 + i * 16 + l15;
        int cid = (((ks * 4) + l4) ^ (row & 7)) << 3;
        af[i] = *(const s16x8*)&sA[row * 64 + cid];
      }
#pragma unroll
      for (int j = 0; j < 4; ++j) {
        int row = wc * 64 + j * 16 + l15;
        int cid = (((ks * 4) + l4) ^ (row & 7)) << 3;
        bg[j] = *(const s16x8*)&sG[row * 64 + cid];
        bu[j] = *(const s16x8*)&sU[row * 64 + cid];
      }
#pragma unroll
      for (int i = 0; i < 4; ++i)
#pragma unroll
        for (int j = 0; j < 4; ++j) {
          accg[i][j] = __builtin_amdgcn_mfma_f32_16x16x32_bf16(af[i], bg[j], accg[i][j], 0, 0, 0);
          accu[i][j] = __builtin_amdgcn_mfma_f32_16x16x32_bf16(af[i], bu[j], accu[i][j], 0, 0, 0);
        }
    }
    __syncthreads();
  }

  const int r0 = m0 + wr * 64 + (l4 << 2);
  const int c0 = n0 + wc * 64 + l15;
#pragma unroll
  for (int i = 0; i < 4; ++i)
#pragma unroll
    for (int j = 0; j < 4; ++j)
#pragma unroll
      for (int r = 0; r < 4; ++r) {
        size_t idx = (size_t)(r0 + i * 16 + r) * N + (c0 + j * 16);
        float g = accg[i][j][r];
        outB[idx] = f2bf(accu[i][j][r] * g / (1.f + __expf(-g)));
      }
}

// ---------------------------------------------------------------------------
// RoPE tables: cos/sin [S][64]
// ---------------------------------------------------------------------------
__global__ void k_ropetab(float* __restrict__ cosT, float* __restrict__ sinT) {
  int idx = blockIdx.x * 256 + threadIdx.x;
  int s = idx >> 6, d = idx & 63;
  float inv = powf(10000.f, -(float)d * (1.f / 64.f));
  float f = (float)s * inv;
  cosT[idx] = cosf(f);
  sinT[idx] = sinf(f);
}

// ---------------------------------------------------------------------------
// K/V prep (once per layer)
// ---------------------------------------------------------------------------
__global__ __launch_bounds__(256) void k_kvprep(const unsigned short* __restrict__ P3,
                                                const float* __restrict__ cosT,
                                                const float* __restrict__ sinT,
                                                unsigned short* __restrict__ kb,
                                                unsigned short* __restrict__ vb) {
  __shared__ unsigned short sT[128 * 72];
  const int tid = threadIdx.x;
  const int bh = blockIdx.y, b = bh >> 5, h = bh & 31;
  const int k0 = blockIdx.x * 64;
  { // K rows: RoPE -> kb (coalesced)
    int row = tid >> 2, part = tid & 3;
    int ksr = k0 + row;
    const unsigned short* kp = P3 + (size_t)(b * SS + ksr) * N3 + 4096 + h * HD_;
    const float* cr = cosT + ksr * 64;
    const float* sr = sinT + ksr * 64;
    unsigned short* kd = kb + ((size_t)bh * SS + ksr) * HD_;
#pragma unroll
    for (int g = 0; g < 2; ++g) {
      int d0 = part * 16 + g * 8;
      u16x8t klo = *(const u16x8t*)(kp + d0);
      u16x8t khi = *(const u16x8t*)(kp + d0 + 64);
      u16x8t wlo, whi;
#pragma unroll
      for (int j = 0; j < 8; ++j) {
        float lo = b2f(klo[j]), hi = b2f(khi[j]);
        float c = cr[d0 + j], s = sr[d0 + j];
        wlo[j] = f2bf(lo * c - hi * s);
        whi[j] = f2bf(hi * c + lo * s);
      }
      *(u16x8t*)(kd + d0)      = wlo;
      *(u16x8t*)(kd + d0 + 64) = whi;
    }
  }
  { // V transpose via LDS -> vb rows
#pragma unroll
    for (int it = 0; it < 8; ++it) {
      int key = it * 8 + (tid >> 5), hd0 = (tid & 31) * 4;
      u16x4t v = *(const u16x4t*)(P3 + (size_t)(b * SS + k0 + key) * N3 + 8192 + h * HD_ + hd0);
      sT[(hd0 + 0) * 72 + key] = v.x;
      sT[(hd0 + 1) * 72 + key] = v.y;
      sT[(hd0 + 2) * 72 + key] = v.z;
      sT[(hd0 + 3) * 72 + key] = v.w;
    }
    __syncthreads();
    int hd = tid >> 1, half = tid & 1;
    unsigned short* vd = vb + ((size_t)bh * HD_ + hd) * SS + k0 + half * 32;
    const unsigned short* ssrc = sT + hd * 72 + half * 32;
#pragma unroll
    for (int j = 0; j < 4; ++j)
      *(u16x8t*)(vd + j * 8) = *(const u16x8t*)(ssrc + j * 8);
  }
}

// ---------------------------------------------------------------------------
// Flash attention (Q-RoPE in-register; K/V DMA from prepped buffers,
// pre-swizzled source + linear LDS + swizzled ds_read)
// ---------------------------------------------------------------------------
__global__ __launch_bounds__(256, 3) void k_attn(const unsigned short* __restrict__ P3,
                                                 const unsigned short* __restrict__ kb,
                                                 const unsigned short* __restrict__ vb,
                                                 const float* __restrict__ cosT,
                                                 const float* __restrict__ sinT,
                                                 const int* __restrict__ am,
                                                 unsigned short* __restrict__ O) {
  __shared__ unsigned short sK[64 * 128];
  __shared__ unsigned short sV[128 * 64];
  __shared__ unsigned short sP[4 * 16 * 72];
  const int tid = threadIdx.x, wave = tid >> 6, lane = tid & 63;
  const int bh = blockIdx.y, b = bh >> 5, h = bh & 31;
  const int qt = (int)gridDim.x - 1 - blockIdx.x;
  const float scale = 0.08838834764831845f;
  const int l15 = lane & 15, l4 = lane >> 4;

  const int qs = qt * 64 + wave * 16 + l15;
  s16x8 qf[4];
  {
    const unsigned short* qp = P3 + (size_t)(b * SS + qs) * N3 + h * HD_;
    const float* cr = cosT + qs * 64;
    const float* sr = sinT + qs * 64;
#pragma unroll
    for (int ks = 0; ks < 2; ++ks) {
      int dlo = ks * 32 + l4 * 8;
      u16x8t qlo = *(const u16x8t*)(qp + dlo);
      u16x8t qhi = *(const u16x8t*)(qp + dlo + 64);
      u16x8t plo, phi;
#pragma unroll
      for (int j = 0; j < 8; ++j) {
        float lo = b2f(qlo[j]), hi = b2f(qhi[j]);
        float c = cr[dlo + j], s = sr[dlo + j];
        plo[j] = f2bf(lo * c - hi * s);
        phi[j] = f2bf(hi * c + lo * s);
      }
      qf[ks]     = *(s16x8*)&plo;
      qf[ks + 2] = *(s16x8*)&phi;
    }
  }

  const int krow_l = lane >> 4, kg = lane & 15;
  const int vrow_l = lane >> 3, vg = lane & 7;

  fx4 oacc[8];
#pragma unroll
  for (int nf = 0; nf < 8; ++nf) oacc[nf] = (fx4){0.f, 0.f, 0.f, 0.f};
  float mrun[4] = {-1e30f, -1e30f, -1e30f, -1e30f};
  float lrun[4] = {0.f, 0.f, 0.f, 0.f};

  const int ntiles = qt + 1;
  for (int kt = 0; kt < ntiles; ++kt) {
    const int k0 = kt * 64;
    __syncthreads();
#pragma unroll
    for (int i = 0; i < 4; ++i) {
      int row = (i * 4 + wave) * 4 + krow_l;
      const unsigned short* gp = kb + ((size_t)bh * SS + k0 + row) * HD_ + ((kg ^ (row & 7)) << 3);
      unsigned short* lp = sK + (i * 4 + wave) * 512;
      __builtin_amdgcn_global_load_lds(
          (const __attribute__((address_space(1))) unsigned int*)gp,
          (__attribute__((address_space(3))) unsigned int*)lp, 16, 0, 0);
    }
#pragma unroll
    for (int i = 0; i < 4; ++i) {
      int row = (i * 4 + wave) * 8 + vrow_l;
      const unsigned short* gp = vb + ((size_t)bh * HD_ + row) * SS + k0 + ((vg ^ (row & 7)) << 3);
      unsigned short* lp = sV + (i * 4 + wave) * 512;
      __builtin_amdgcn_global_load_lds(
          (const __attribute__((address_space(1))) unsigned int*)gp,
          (__attribute__((address_space(3))) unsigned int*)lp, 16, 0, 0);
    }
    __syncthreads();
    if (k0 <= qt * 64 + wave * 16 + 15) {
      fx4 sfr[4];
#pragma unroll
      for (int kf = 0; kf < 4; ++kf) sfr[kf] = (fx4){0.f, 0.f, 0.f, 0.f};
#pragma unroll
      for (int kf = 0; kf < 4; ++kf) {
        int row = kf * 16 + l15;
#pragma unroll
        for (int ks = 0; ks < 4; ++ks) {
          int cid = ((ks * 4 + l4) ^ (row & 7)) << 3;
          s16x8 kfr = *(const s16x8*)&sK[row * 128 + cid];
          sfr[kf] = __builtin_amdgcn_mfma_f32_16x16x32_bf16(qf[ks], kfr, sfr[kf], 0, 0, 0);
        }
      }
      float p[16], corr[4];
#pragma unroll
      for (int r = 0; r < 4; ++r) {
        int qr = qt * 64 + wave * 16 + l4 * 4 + r;
        float mx = -1e30f;
#pragma unroll
        for (int kf = 0; kf < 4; ++kf) {
          int key = k0 + kf * 16 + l15;
          float bb = (key <= qr && am[b * SS + key] != 0) ? 0.f : -1e9f;
          p[kf * 4 + r] = sfr[kf][r] * scale + bb;
          mx = fmaxf(mx, p[kf * 4 + r]);
        }
        mx = fmaxf(mx, __shfl_xor(mx, 1));
        mx = fmaxf(mx, __shfl_xor(mx, 2));
        mx = fmaxf(mx, __shfl_xor(mx, 4));
        mx = fmaxf(mx, __shfl_xor(mx, 8));
        float mn = fmaxf(mrun[r], mx);
        corr[r] = __expf(mrun[r] - mn);
        mrun[r] = mn;
        float rs = 0.f;
#pragma unroll
        for (int kf = 0; kf < 4; ++kf) {
          p[kf * 4 + r] = __expf(p[kf * 4 + r] - mn);
          rs += p[kf * 4 + r];
        }
        rs += __shfl_xor(rs, 1);
        rs += __shfl_xor(rs, 2);
        rs += __shfl_xor(rs, 4);
        rs += __shfl_xor(rs, 8);
        lrun[r] = lrun[r] * corr[r] + rs;
      }
#pragma unroll
      for (int nf = 0; nf < 8; ++nf) {
        oacc[nf][0] *= corr[0];
        oacc[nf][1] *= corr[1];
        oacc[nf][2] *= corr[2];
        oacc[nf][3] *= corr[3];
      }
      unsigned short* pp = sP + wave * (16 * 72);
#pragma unroll
      for (int r = 0; r < 4; ++r) {
        int row = l4 * 4 + r;
#pragma unroll
        for (int kf = 0; kf < 4; ++kf)
          pp[row * 72 + kf * 16 + l15] = f2bf(p[kf * 4 + r]);
      }
      s16x8 pa0 = *(const s16x8*)&pp[l15 * 72 + l4 * 8];
      s16x8 pa1 = *(const s16x8*)&pp[l15 * 72 + 32 + l4 * 8];
#pragma unroll
      for (int nf = 0; nf < 8; ++nf) {
        int row = nf * 16 + l15;
        int c0s = ((0 * 4 + l4) ^ (row & 7)) << 3;
        int c1s = ((1 * 4 + l4) ^ (row & 7)) << 3;
        s16x8 v0 = *(const s16x8*)&sV[row * 64 + c0s];
        s16x8 v1 = *(const s16x8*)&sV[row * 64 + c1s];
        oacc[nf] = __builtin_amdgcn_mfma_f32_16x16x32_bf16(pa0, v0, oacc[nf], 0, 0, 0);
        oacc[nf] = __builtin_amdgcn_mfma_f32_16x16x32_bf16(pa1, v1, oacc[nf], 0, 0, 0);
      }
    }
  }
  const size_t obase = (size_t)b * SS * D_ + h * HD_;
#pragma unroll
  for (int nf = 0; nf < 8; ++nf)
#pragma unroll
    for (int r = 0; r < 4; ++r) {
      int qr = qt * 64 + wave * 16 + l4 * 4 + r;
      O[obase + (size_t)qr * D_ + nf * 16 + l15] = f2bf(oacc[nf][r] / lrun[r]);
    }
}

// ---------------------------------------------------------------------------
// Final RMSNorm + classifier
// ---------------------------------------------------------------------------
__global__ __launch_bounds__(256) void k_final(const float* __restrict__ xf,
                                               const float* __restrict__ fw,
                                               const float* __restrict__ cW,
                                               const float* __restrict__ cb,
                                               float* __restrict__ out) {
  const int b = blockIdx.x, tid = threadIdx.x;
  const float* xr = xf + (size_t)b * SS * D_;
  __shared__ float red[4];
  fx4 v[4];
  float ss = 0.f;
#pragma unroll
  for (int i = 0; i < 4; ++i) {
    v[i] = *(const fx4*)(xr + i * 1024 + tid * 4);
    ss += v[i][0]*v[i][0] + v[i][1]*v[i][1] + v[i][2]*v[i][2] + v[i][3]*v[i][3];
  }
#pragma unroll
  for (int off = 32; off > 0; off >>= 1) ss += __shfl_down(ss, off);
  if ((tid & 63) == 0) red[tid >> 6] = ss;
  __syncthreads();
  const float sc = rsqrtf((red[0] + red[1] + red[2] + red[3]) * (1.f / D_) + EPS_);
  for (int c = 0; c < 3; ++c) {
    float d = 0.f;
#pragma unroll
    for (int i = 0; i < 4; ++i) {
      fx4 fv = *(const fx4*)(fw + i * 1024 + tid * 4);
      fx4 cw = *(const fx4*)(cW + (size_t)c * D_ + i * 1024 + tid * 4);
#pragma unroll
      for (int j = 0; j < 4; ++j) d += v[i][j] * sc * fv[j] * cw[j];
    }
#pragma unroll
    for (int off = 32; off > 0; off >>= 1) d += __shfl_down(d, off);
    __syncthreads();
    if ((tid & 63) == 0) red[tid >> 6] = d;
    __syncthreads();
    if (tid == 0) out[b * 3 + c] = red[0] + red[1] + red[2] + red[3] + cb[c];
  }
}

// ---------------------------------------------------------------------------
extern "C" void kernel_launch(void* const* d_in, const int* in_sizes, int n_in,
                              void* d_out, int out_size, void* d_ws, size_t ws_size,
                              hipStream_t stream) {
  const int*   ids = (const int*)d_in[0];
  const int*   am  = (const int*)d_in[1];
  const float* emb = (const float*)d_in[2];
  const float* Wq  = (const float*)d_in[3];
  const float* Wk  = (const float*)d_in[4];
  const float* Wv  = (const float*)d_in[5];
  const float* Wo  = (const float*)d_in[6];
  const float* Aq  = (const float*)d_in[7];
  const float* Bq  = (const float*)d_in[8];
  const float* Ak  = (const float*)d_in[9];
  const float* Bk  = (const float*)d_in[10];
  const float* Av  = (const float*)d_in[11];
  const float* Bv  = (const float*)d_in[12];
  const float* Ao  = (const float*)d_in[13];
  const float* Bo  = (const float*)d_in[14];
  const float* Wg  = (const float*)d_in[15];
  const float* Wu  = (const float*)d_in[16];
  const float* Wd  = (const float*)d_in[17];
  const float* anw = (const float*)d_in[18];
  const float* mnw = (const float*)d_in[19];
  const float* fnw = (const float*)d_in[20];
  const float* cW  = (const float*)d_in[21];
  const float* cb  = (const float*)d_in[22];
  float* out = (float*)d_out;

  char* w = (char*)d_ws;
  float* xf = (float*)w;                     w += (size_t)TOK * D_ * 4;
  unsigned short* P3 = (unsigned short*)w;   w += (size_t)TOK * N3 * 2;
  unsigned short* gact = (unsigned short*)w; w += (size_t)TOK * F_ * 2;
  unsigned short* hb = (unsigned short*)w;   w += (size_t)TOK * D_ * 2;
  unsigned short* ob = (unsigned short*)w;   w += (size_t)TOK * D_ * 2;
  unsigned short* kbuf = (unsigned short*)w; w += (size_t)TOK * D_ * 2;
  unsigned short* vbuf = (unsigned short*)w; w += (size_t)TOK * D_ * 2;
  unsigned short* Wm3 = (unsigned short*)w;  w += (size_t)3 * D_ * D_ * 2;
  unsigned short* Wgu = (unsigned short*)w;  w += (size_t)2 * F_ * D_ * 2;
  unsigned short* Bx3 = (unsigned short*)w;  w += (size_t)3 * D_ * R_ * 2;
  unsigned short* BxO = (unsigned short*)w;  w += (size_t)D_ * R_ * 2;
  unsigned short* lm3 = (unsigned short*)w;  w += (size_t)TOK * 192 * 2;
  unsigned short* lmo = (unsigned short*)w;  w += (size_t)TOK * 64 * 2;
  float* lm3p = (float*)w;                   w += (size_t)8 * TOK * 192 * 4;
  float* lmop = (float*)w;                   w += (size_t)8 * TOK * 64 * 4;
  float* cosT = (float*)w;                   w += (size_t)SS * 64 * 4;
  float* sinT = (float*)w;                   w += (size_t)SS * 64 * 4;
  if ((size_t)(w - (char*)d_ws) > ws_size) return;

  k_ropetab<<<256, 256, 0, stream>>>(cosT, sinT);
  k_embed<<<TOK, 256, 0, stream>>>(ids, emb, xf);

  const int nwgQKV = (N3 / 128) * (TOK / 128);   // 1536
  const int nwgProj = (D_ / 128) * (TOK / 128);  // 512
  const int nwgMlp = (F_ / 128) * (TOK / 128);   // 1376
  dim3 gAttn(SS / 64, BB * H_);
  dim3 gPrep(SS / 64, BB * H_);
  dim3 gLmid(TOK / 64, 8);
  const int CVT_BLK = 2048;

  for (int l = 0; l < L_; ++l) {
    const size_t oDD = (size_t)l * D_ * D_;
    const size_t oRD = (size_t)l * R_ * D_;
    const size_t oDR = (size_t)l * D_ * R_;
    const size_t oFD = (size_t)l * F_ * D_;

    k_rmsnorm<<<TOK, 256, 0, stream>>>(xf, anw + (size_t)l * D_, hb);
    // QKV: merged cvt (W x3, B x3), LoRA mid, single-tile fused GEMM (R13 cfg)
    k_cvtN<<<dim3(CVT_BLK, 3), 256, 0, stream>>>(Wq + oDD, Wk + oDD, Wv + oDD, Wm3, D_ * D_);
    k_cvtN<<<dim3(128, 3), 256, 0, stream>>>(Bq + oDR, Bk + oDR, Bv + oDR, Bx3, D_ * R_);
    k_lmid<12><<<gLmid, 256, 0, stream>>>(hb, Aq + oRD, Ak + oRD, Av + oRD, lm3p);
    k_lmred<<<TOK * 192 / 256, 256, 0, stream>>>(lm3p, lm3, 192);
    k_gemm<5, true><<<nwgQKV, 256, 0, stream>>>(hb, Wm3, nullptr, P3, nullptr,
                                                lm3, 192, Bx3, TOK, N3, D_, nwgQKV);
    // K/V prep + attention
    k_kvprep<<<gPrep, 256, 0, stream>>>(P3, cosT, sinT, kbuf, vbuf);
    k_attn<<<gAttn, 256, 0, stream>>>(P3, kbuf, vbuf, cosT, sinT, am, ob);
    // O projection + LoRA ext + residual
    k_cvtN<<<dim3(CVT_BLK, 1), 256, 0, stream>>>(Wo + oDD, nullptr, nullptr, Wm3, D_ * D_);
    k_cvtN<<<dim3(128, 1), 256, 0, stream>>>(Bo + oDR, nullptr, nullptr, BxO, D_ * R_);
    k_lmid<4><<<gLmid, 256, 0, stream>>>(ob, Ao + oRD, Ao + oRD, Ao + oRD, lmop);
    k_lmred<<<TOK * 64 / 256, 256, 0, stream>>>(lmop, lmo, 64);
    k_gemm<2, true><<<nwgProj, 256, 0, stream>>>(ob, Wm3, xf, nullptr, xf,
                                                 lmo, 64, BxO, TOK, D_, D_, nwgProj);
    // MLP
    k_rmsnorm<<<TOK, 256, 0, stream>>>(xf, mnw + (size_t)l * D_, hb);
    k_cvtN<<<dim3(CVT_BLK, 2), 256, 0, stream>>>(Wg + oFD, Wu + oFD, nullptr, Wgu, F_ * D_);
    k_gemm_gu2<<<nwgMlp, 256, 0, stream>>>(hb, Wgu, Wgu + (size_t)F_ * D_, gact, TOK, F_, D_, nwgMlp);
    k_cvtN<<<dim3(CVT_BLK, 1), 256, 0, stream>>>(Wd + oFD, nullptr, nullptr, Wgu, D_ * F_);
    k_gemm<2, false><<<nwgProj, 256, 0, stream>>>(gact, Wgu, xf, nullptr, xf,
                                                  nullptr, 0, nullptr, TOK, D_, F_, nwgProj);
  }

  k_final<<<BB, 256, 0, stream>>>(xf, fnw, cW, cb, out);
  (void)in_sizes; (void)n_in; (void)out_size;
}